// Round 17
// baseline (243.420 us; speedup 1.0000x reference)
//
#include <hip/hip_runtime.h>
#include <hip/hip_bf16.h>
#include <hip/hip_cooperative_groups.h>
#include <math.h>

#define N_NODES 50000
#define N_EDGES 800000
#define EP (N_EDGES + N_NODES)   /* 850000 edges incl. self-loops */
#define HID 64
#define HEADS 4
#define F1 (HEADS * HID)         /* 256 */
#define NC 16
#define SLOPE 0.2f
#define NRT 3125                 /* row tiles: 50000 = 16*3125 exactly */
#define GMB 2048                 /* gemm grid blocks */
#define NT 49                    /* scan tiles = ceil(N/1024) */

typedef __attribute__((ext_vector_type(8))) short short8;
typedef __attribute__((ext_vector_type(4))) float f32x4;

// ---- bf16 helpers (round-to-nearest-even pack, exact unpack) ----
__device__ __forceinline__ unsigned short bf16rn(float f) {
    unsigned u = __float_as_uint(f);
    return (unsigned short)((u + 0x7fffu + ((u >> 16) & 1u)) >> 16);
}
__device__ __forceinline__ float bf_lo(unsigned p) { return __uint_as_float(p << 16); }
__device__ __forceinline__ float bf_hi(unsigned p) { return __uint_as_float(p & 0xffff0000u); }

__device__ __forceinline__ void edge_sd(int e, const int* __restrict__ ei, int& s, int& d) {
    if (e < N_EDGES) { s = ei[e]; d = ei[N_EDGES + e]; }
    else             { s = e - N_EDGES; d = s; }
}

// ------- CSR build, single cooperative kernel: local scan | top scan | add | scatter -------
__global__ __launch_bounds__(1024) void k_csr_build(
        const int* __restrict__ ei, const int* __restrict__ cnt,
        int* __restrict__ row_start, int* __restrict__ cursor,
        int* __restrict__ esrc, int* __restrict__ bsum) {
    cooperative_groups::grid_group grid = cooperative_groups::this_grid();
    __shared__ int wsum[16];
    int t = threadIdx.x, lane = t & 63, wid = t >> 6;
    int i = blockIdx.x * 1024 + t;
    // ---- phase 1: block-local exclusive scan of cnt ----
    int v = (i < N_NODES) ? cnt[i] : 0;
    int s = v;
#pragma unroll
    for (int off = 1; off < 64; off <<= 1) {
        int x = __shfl_up(s, off);
        if (lane >= off) s += x;
    }
    if (lane == 63) wsum[wid] = s;
    __syncthreads();
    if (t < 16) {
        int w = wsum[t];
#pragma unroll
        for (int off = 1; off < 16; off <<= 1) {
            int x = __shfl_up(w, off);
            if (t >= off) w += x;
        }
        wsum[t] = w;
    }
    __syncthreads();
    int waveoff = (wid == 0) ? 0 : wsum[wid - 1];
    int incl = s + waveoff;
    if (i < N_NODES) row_start[i] = incl - v;
    if (t == 1023) bsum[blockIdx.x] = incl;
    grid.sync();
    // ---- phase 2: top scan of the 49 block sums (block 0, one wave) ----
    if (blockIdx.x == 0 && t < 64) {
        int bv = (t < NT) ? bsum[t] : 0;
        int bs = bv;
#pragma unroll
        for (int off = 1; off < 64; off <<= 1) {
            int x = __shfl_up(bs, off);
            if (t >= off) bs += x;
        }
        if (t < NT) bsum[t] = bs - bv;
        if (t == 63) row_start[N_NODES] = bs;
    }
    grid.sync();
    // ---- phase 3: add block offsets; init cursor ----
    if (i < N_NODES) {
        int vv = row_start[i] + bsum[i >> 10];
        row_start[i] = vv;
        cursor[i] = vv;
    }
    grid.sync();
    // ---- phase 4: scatter src ids into dst-sorted order ----
    for (int e = blockIdx.x * 1024 + t; e < EP; e += NT * 1024) {
        int s2, d2; edge_sd(e, ei, s2, d2);
        int p = atomicAdd(&cursor[d2], 1);
        esrc[p] = s2;
    }
}

// ------- layer 1 GEMM via MFMA bf16 (16x16x32) + fused edge histogram -------
__global__ __launch_bounds__(256) void k_gemm1(
        const float* __restrict__ x, const float* __restrict__ W1,
        const float* __restrict__ att_s, const float* __restrict__ att_d,
        unsigned short* __restrict__ xh1b, float* __restrict__ a_src, float* __restrict__ a_dst,
        const int* __restrict__ ei, int* __restrict__ cnt) {
    __shared__ float xs[16][68];          // padded x-tile (4.4 KB)
    int t = threadIdx.x;
    for (int e = blockIdx.x * 256 + t; e < EP; e += 256 * GMB) {
        int s, d; edge_sd(e, ei, s, d);
        atomicAdd(&cnt[d], 1);
    }
    int w = t >> 6, l = t & 63;
    int lo16 = l & 15, kg = l >> 4;       // B col / A row ; k-group
    short8 bfrag[4][2];
#pragma unroll
    for (int ct = 0; ct < 4; ++ct)
#pragma unroll
        for (int kh = 0; kh < 2; ++kh) {
            const float* wp = W1 + (size_t)(kh * 32 + kg * 8) * F1 + (w * 64 + ct * 16 + lo16);
            short8 f;
#pragma unroll
            for (int i = 0; i < 8; ++i) f[i] = (short)bf16rn(wp[(size_t)i * F1]);
            bfrag[ct][kh] = f;
        }
    float asv[4], adv[4];
#pragma unroll
    for (int ct = 0; ct < 4; ++ct) {
        asv[ct] = att_s[w * 64 + ct * 16 + lo16];
        adv[ct] = att_d[w * 64 + ct * 16 + lo16];
    }
    int sr = t >> 4, sc = (t & 15) * 4;   // staging coords
    for (int rt = blockIdx.x; rt < NRT; rt += GMB) {
        __syncthreads();                  // WAR on xs
        *(float4*)&xs[sr][sc] = *(const float4*)(x + (size_t)(rt * 16 + sr) * HID + sc);
        __syncthreads();
        short8 af[2];
#pragma unroll
        for (int kh = 0; kh < 2; ++kh) {
            const float* xp = &xs[lo16][kh * 32 + kg * 8];
            float4 u0 = *(const float4*)xp;
            float4 u1 = *(const float4*)(xp + 4);
            short8 f;
            f[0] = (short)bf16rn(u0.x); f[1] = (short)bf16rn(u0.y);
            f[2] = (short)bf16rn(u0.z); f[3] = (short)bf16rn(u0.w);
            f[4] = (short)bf16rn(u1.x); f[5] = (short)bf16rn(u1.y);
            f[6] = (short)bf16rn(u1.z); f[7] = (short)bf16rn(u1.w);
            af[kh] = f;
        }
        f32x4 acc[4];
#pragma unroll
        for (int ct = 0; ct < 4; ++ct) {
            acc[ct] = (f32x4){0.f, 0.f, 0.f, 0.f};
            acc[ct] = __builtin_amdgcn_mfma_f32_16x16x32_bf16(af[0], bfrag[ct][0], acc[ct], 0, 0, 0);
            acc[ct] = __builtin_amdgcn_mfma_f32_16x16x32_bf16(af[1], bfrag[ct][1], acc[ct], 0, 0, 0);
        }
#pragma unroll
        for (int reg = 0; reg < 4; ++reg) {
            int gr = rt * 16 + kg * 4 + reg;
#pragma unroll
            for (int ct = 0; ct < 4; ++ct)
                xh1b[(size_t)gr * F1 + w * 64 + ct * 16 + lo16] = bf16rn(acc[ct][reg]);
            float ps = acc[0][reg] * asv[0] + acc[1][reg] * asv[1]
                     + acc[2][reg] * asv[2] + acc[3][reg] * asv[3];
            float pd = acc[0][reg] * adv[0] + acc[1][reg] * adv[1]
                     + acc[2][reg] * adv[2] + acc[3][reg] * adv[3];
#pragma unroll
            for (int o = 1; o <= 8; o <<= 1) {
                ps += __shfl_xor(ps, o);
                pd += __shfl_xor(pd, o);
            }
            if (lo16 == 0) {
                a_src[gr * HEADS + w] = ps;
                a_dst[gr * HEADS + w] = pd;
            }
        }
    }
}

// ------- layer 1, wave-per-node: no-max softmax + wide gather + ELU + (h @ W2) -------
// lal padded [4][4][68]: hf slices on distinct banks -> conflict-free alpha reads.
__global__ __launch_bounds__(256) void k_csr1(
        const int* __restrict__ row_start, const int* __restrict__ esrc,
        const float* __restrict__ a_src, const float* __restrict__ a_dst,
        const unsigned short* __restrict__ xh1b, const float* __restrict__ b1,
        const float* __restrict__ W2, const float* __restrict__ att_s2,
        const float* __restrict__ att_d2,
        unsigned short* __restrict__ xh2b, float* __restrict__ a_src2,
        float* __restrict__ a_dst2) {
    int w = threadIdx.x >> 6, l = threadIdx.x & 63;
    int d = blockIdx.x * 4 + w;
    if (d >= N_NODES) return;
    int base = row_start[d], deg = row_start[d + 1] - base;
    __shared__ int   ls[4][64];
    __shared__ float lal[4][4][68];      // [wave][head][edge(+pad)]
    int h = l >> 4, e16 = l & 15;        // softmax mapping
    int eoff = l >> 5, fl = l & 31, hf = fl >> 3;   // gather mapping
    int* lsw = ls[w];
    float adh = a_dst[d * HEADS + h];
    float denl = 0.0f;
    float a0=0.f,a1=0.f,a2=0.f,a3=0.f,a4=0.f,a5=0.f,a6=0.f,a7=0.f;
    for (int c0 = 0; c0 < deg; c0 += 64) {
        int cn = min(64, deg - c0);
        if (l < cn) lsw[l] = esrc[base + c0 + l];
        // ---- single-pass softmax weights (no max subtraction; logits small) ----
        for (int j = e16; j < cn; j += 16) {
            float ev = a_src[lsw[j] * HEADS + h] + adh;
            ev = ev > 0.0f ? ev : SLOPE * ev;
            float wj = __expf(ev);
            lal[w][h][j] = wj;           // same-wave RAW below
            denl += wj;
        }
        // ---- wide gather: 2 edges per uint4 instr, 4 edges in flight ----
        const float* lalh = lal[w][hf];
        int j = 0;
        for (; j + 3 < cn; j += 4) {
            float wa = lalh[j + eoff], wb = lalh[j + 2 + eoff];
            uint4 pa = *(const uint4*)(xh1b + (size_t)lsw[j + eoff]     * F1 + 8 * fl);
            uint4 pb = *(const uint4*)(xh1b + (size_t)lsw[j + 2 + eoff] * F1 + 8 * fl);
            a0 += wa * bf_lo(pa.x); a1 += wa * bf_hi(pa.x);
            a2 += wa * bf_lo(pa.y); a3 += wa * bf_hi(pa.y);
            a4 += wa * bf_lo(pa.z); a5 += wa * bf_hi(pa.z);
            a6 += wa * bf_lo(pa.w); a7 += wa * bf_hi(pa.w);
            a0 += wb * bf_lo(pb.x); a1 += wb * bf_hi(pb.x);
            a2 += wb * bf_lo(pb.y); a3 += wb * bf_hi(pb.y);
            a4 += wb * bf_lo(pb.z); a5 += wb * bf_hi(pb.z);
            a6 += wb * bf_lo(pb.w); a7 += wb * bf_hi(pb.w);
        }
        for (; j + 1 < cn; j += 2) {
            float wa = lalh[j + eoff];
            uint4 pa = *(const uint4*)(xh1b + (size_t)lsw[j + eoff] * F1 + 8 * fl);
            a0 += wa * bf_lo(pa.x); a1 += wa * bf_hi(pa.x);
            a2 += wa * bf_lo(pa.y); a3 += wa * bf_hi(pa.y);
            a4 += wa * bf_lo(pa.z); a5 += wa * bf_hi(pa.z);
            a6 += wa * bf_lo(pa.w); a7 += wa * bf_hi(pa.w);
        }
        if (j < cn && eoff == 0) {       // odd tail: low half only
            float wa = lalh[j];
            uint4 pa = *(const uint4*)(xh1b + (size_t)lsw[j] * F1 + 8 * fl);
            a0 += wa * bf_lo(pa.x); a1 += wa * bf_hi(pa.x);
            a2 += wa * bf_lo(pa.y); a3 += wa * bf_hi(pa.y);
            a4 += wa * bf_lo(pa.z); a5 += wa * bf_hi(pa.z);
            a6 += wa * bf_lo(pa.w); a7 += wa * bf_hi(pa.w);
        }
    }
    // den: reduce within 16-lane head group, then fetch my gather-head's den
#pragma unroll
    for (int o = 8; o >= 1; o >>= 1) denl += __shfl_xor(denl, o);
    float dd = __shfl(denl, hf * 16);
    float inv = 1.0f / (dd + 1e-16f);
    // merge edge halves
    a0 += __shfl_xor(a0, 32); a1 += __shfl_xor(a1, 32);
    a2 += __shfl_xor(a2, 32); a3 += __shfl_xor(a3, 32);
    a4 += __shfl_xor(a4, 32); a5 += __shfl_xor(a5, 32);
    a6 += __shfl_xor(a6, 32); a7 += __shfl_xor(a7, 32);
    // bias + ELU for features 8*fl..8*fl+7
    float4 bb0 = *(const float4*)(b1 + 8 * fl);
    float4 bb1 = *(const float4*)(b1 + 8 * fl + 4);
    float v0 = a0 * inv + bb0.x, v1 = a1 * inv + bb0.y;
    float v2 = a2 * inv + bb0.z, v3 = a3 * inv + bb0.w;
    float v4 = a4 * inv + bb1.x, v5 = a5 * inv + bb1.y;
    float v6 = a6 * inv + bb1.z, v7 = a7 * inv + bb1.w;
    v0 = v0 > 0.0f ? v0 : (__expf(v0) - 1.0f);
    v1 = v1 > 0.0f ? v1 : (__expf(v1) - 1.0f);
    v2 = v2 > 0.0f ? v2 : (__expf(v2) - 1.0f);
    v3 = v3 > 0.0f ? v3 : (__expf(v3) - 1.0f);
    v4 = v4 > 0.0f ? v4 : (__expf(v4) - 1.0f);
    v5 = v5 > 0.0f ? v5 : (__expf(v5) - 1.0f);
    v6 = v6 > 0.0f ? v6 : (__expf(v6) - 1.0f);
    v7 = v7 > 0.0f ? v7 : (__expf(v7) - 1.0f);
    // ---- stage h row (same wave; lanes<32 hold the merged sums) ----
    float* hrow = &lal[w][0][0];          // flat reuse (>=256 floats)
    if (l < 32) {
        *(float4*)(hrow + 8 * fl)     = make_float4(v0, v1, v2, v3);
        *(float4*)(hrow + 8 * fl + 4) = make_float4(v4, v5, v6, v7);
    }
    // ---- projection: flat coalesced W2 (16KB; L1-resident after first wave) ----
    int k0 = l >> 2;                      // h index base (stride 16)
    int cg = (l & 3) * 4;                 // class-group base
    const float4* w4 = (const float4*)W2;
    float q0 = 0.0f, q1 = 0.0f, q2 = 0.0f, q3 = 0.0f;
#pragma unroll
    for (int j = 0; j < 16; ++j) {
        float hk = hrow[k0 + 16 * j];     // 16-addr broadcast, conflict-free
        float4 wv = w4[l + 64 * j];       // coalesced: bytes 16l + 1024j
        q0 += hk * wv.x; q1 += hk * wv.y; q2 += hk * wv.z; q3 += hk * wv.w;
    }
#pragma unroll
    for (int o = 4; o <= 32; o <<= 1) {   // reduce lanes sharing (l&3)
        q0 += __shfl_xor(q0, o); q1 += __shfl_xor(q1, o);
        q2 += __shfl_xor(q2, o); q3 += __shfl_xor(q3, o);
    }
    if (l < 4) {                          // lane l owns classes 4l..4l+3
        unsigned u0 = (unsigned)bf16rn(q0) | ((unsigned)bf16rn(q1) << 16);
        unsigned u1 = (unsigned)bf16rn(q2) | ((unsigned)bf16rn(q3) << 16);
        *(uint2*)(xh2b + (size_t)d * NC + 4 * l) = make_uint2(u0, u1);
        float ps = q0 * att_s2[cg] + q1 * att_s2[cg + 1]
                 + q2 * att_s2[cg + 2] + q3 * att_s2[cg + 3];
        float pd = q0 * att_d2[cg] + q1 * att_d2[cg + 1]
                 + q2 * att_d2[cg + 2] + q3 * att_d2[cg + 3];
        ps += __shfl_xor(ps, 1); ps += __shfl_xor(ps, 2);
        pd += __shfl_xor(pd, 1); pd += __shfl_xor(pd, 2);
        if (l == 0) { a_src2[d] = ps; a_dst2[d] = pd; }
    }
}

// ------- layer 2 fused: no-max softmax + wide gather + bias + log_softmax -------
__global__ __launch_bounds__(256) void k_csr2(
        const int* __restrict__ row_start, const int* __restrict__ esrc,
        const float* __restrict__ a_src2, const float* __restrict__ a_dst2,
        const unsigned short* __restrict__ xh2b, const float* __restrict__ b2,
        float* __restrict__ out) {
    int w = threadIdx.x >> 6, l = threadIdx.x & 63;
    int d = blockIdx.x * 4 + w;
    if (d >= N_NODES) return;
    int base = row_start[d], deg = row_start[d + 1] - base;
    __shared__ int   ls[4][64];
    __shared__ float lal[4][64];
    float adh = a_dst2[d];
    int cp4 = l & 3, je = l >> 2;
    float denl = 0.0f, a0 = 0.0f, a1 = 0.0f, a2 = 0.0f, a3 = 0.0f;
    for (int c0 = 0; c0 < deg; c0 += 64) {
        int cn = min(64, deg - c0);
        if (l < cn) {
            int s = esrc[base + c0 + l];
            ls[w][l] = s;
            float ev = a_src2[s] + adh;
            ev = ev > 0.0f ? ev : SLOPE * ev;
            float wj = __expf(ev);
            lal[w][l] = wj;          // same-wave RAW below
            denl += wj;
        }
        for (int j = je; j < cn; j += 16) {
            float wj = lal[w][j];
            uint2 pv = *(const uint2*)(xh2b + (size_t)ls[w][j] * NC + 4 * cp4);
            a0 += wj * bf_lo(pv.x); a1 += wj * bf_hi(pv.x);
            a2 += wj * bf_lo(pv.y); a3 += wj * bf_hi(pv.y);
        }
    }
#pragma unroll
    for (int o = 32; o >= 1; o >>= 1) denl += __shfl_xor(denl, o);
#pragma unroll
    for (int o = 4; o <= 32; o <<= 1) {           // reduce over the 16 je slots
        a0 += __shfl_xor(a0, o); a1 += __shfl_xor(a1, o);
        a2 += __shfl_xor(a2, o); a3 += __shfl_xor(a3, o);
    }
    float inv = 1.0f / (denl + 1e-16f);
    float v0 = a0 * inv + b2[4 * cp4 + 0];
    float v1 = a1 * inv + b2[4 * cp4 + 1];
    float v2 = a2 * inv + b2[4 * cp4 + 2];
    float v3 = a3 * inv + b2[4 * cp4 + 3];
    float mm = fmaxf(fmaxf(v0, v1), fmaxf(v2, v3));
    mm = fmaxf(mm, __shfl_xor(mm, 1));
    mm = fmaxf(mm, __shfl_xor(mm, 2));
    float se = __expf(v0 - mm) + __expf(v1 - mm) + __expf(v2 - mm) + __expf(v3 - mm);
    se += __shfl_xor(se, 1);
    se += __shfl_xor(se, 2);
    float lse = mm + logf(se);
    if (l < 4) *(float4*)(out + (size_t)d * NC + 4 * l)
                   = make_float4(v0 - lse, v1 - lse, v2 - lse, v3 - lse);
}

extern "C" void kernel_launch(void* const* d_in, const int* in_sizes, int n_in,
                              void* d_out, int out_size, void* d_ws, size_t ws_size,
                              hipStream_t stream) {
    const float* x        = (const float*)d_in[0];
    const int*   ei       = (const int*)d_in[1];
    const float* W1       = (const float*)d_in[2];
    const float* att_src1 = (const float*)d_in[3];
    const float* att_dst1 = (const float*)d_in[4];
    const float* b1       = (const float*)d_in[5];
    const float* W2       = (const float*)d_in[6];
    const float* att_src2 = (const float*)d_in[7];
    const float* att_dst2 = (const float*)d_in[8];
    const float* b2       = (const float*)d_in[9];
    float* out = (float*)d_out;

    // ---- workspace layout ----
    char* p = (char*)d_ws;
    unsigned short* xh1b  = (unsigned short*)p; p += (size_t)N_NODES * F1 * 2;   // 25.6MB
    unsigned short* xh2b  = (unsigned short*)p; p += (size_t)N_NODES * NC * 2;   // 1.6MB
    float* a_src1 = (float*)p; p += (size_t)N_NODES * HEADS * 4;
    float* a_dst1 = (float*)p; p += (size_t)N_NODES * HEADS * 4;
    float* a_src2 = (float*)p; p += (size_t)N_NODES * 4;
    float* a_dst2 = (float*)p; p += (size_t)N_NODES * 4;
    int* cnt       = (int*)p;  p += (size_t)N_NODES * 4;
    int* cursor    = (int*)p;  p += (size_t)N_NODES * 4;
    int* row_start = (int*)p;  p += (size_t)(N_NODES + 1) * 4;
    int* bsum      = (int*)p;  p += 64 * 4;
    int* esrc      = (int*)p;  p += (size_t)EP * 4;

    // ---- CSR build: hist fused into gemm1; scan+scatter in ONE cooperative kernel ----
    hipMemsetAsync(cnt, 0, (size_t)N_NODES * 4, stream);
    k_gemm1<<<GMB, 256, 0, stream>>>(x, W1, att_src1, att_dst1, xh1b, a_src1, a_dst1,
                                     ei, cnt);
    {
        void* args[] = { (void*)&ei, (void*)&cnt, (void*)&row_start,
                         (void*)&cursor, (void*)&esrc, (void*)&bsum };
        hipLaunchCooperativeKernel((const void*)k_csr_build, dim3(NT), dim3(1024),
                                   args, 0, stream);
    }

    // ---- layer 1 (+ fused layer-2 projection), wave-per-node ----
    k_csr1<<<(N_NODES + 3) / 4, 256, 0, stream>>>(row_start, esrc, a_src1, a_dst1, xh1b, b1,
                                                  W2, att_src2, att_dst2, xh2b, a_src2, a_dst2);

    // ---- layer 2 ----
    k_csr2<<<(N_NODES + 3) / 4, 256, 0, stream>>>(row_start, esrc, a_src2, a_dst2, xh2b, b2, out);
}

// Round 18
// 209.379 us; speedup vs baseline: 1.1626x; 1.1626x over previous
//
#include <hip/hip_runtime.h>
#include <hip/hip_bf16.h>
#include <math.h>

#define N_NODES 50000
#define N_EDGES 800000
#define EP (N_EDGES + N_NODES)   /* 850000 edges incl. self-loops */
#define HID 64
#define HEADS 4
#define F1 (HEADS * HID)         /* 256 */
#define NC 16
#define SLOPE 0.2f
#define NRT 3125                 /* row tiles: 50000 = 16*3125 exactly */
#define GMB 2048                 /* gemm grid blocks */
#define NT 49                    /* scan tiles = ceil(N/1024) */

typedef __attribute__((ext_vector_type(8))) short short8;
typedef __attribute__((ext_vector_type(4))) float f32x4;

// ---- bf16 helpers (round-to-nearest-even pack, exact unpack) ----
__device__ __forceinline__ unsigned short bf16rn(float f) {
    unsigned u = __float_as_uint(f);
    return (unsigned short)((u + 0x7fffu + ((u >> 16) & 1u)) >> 16);
}
__device__ __forceinline__ float bf_lo(unsigned p) { return __uint_as_float(p << 16); }
__device__ __forceinline__ float bf_hi(unsigned p) { return __uint_as_float(p & 0xffff0000u); }

__device__ __forceinline__ void edge_sd(int e, const int* __restrict__ ei, int& s, int& d) {
    if (e < N_EDGES) { s = ei[e]; d = ei[N_EDGES + e]; }
    else             { s = e - N_EDGES; d = s; }
}

// tile-local exclusive scan: 49 blocks x 1024 threads, 1024 elems/block
__global__ __launch_bounds__(1024) void k_scan_local(const int* __restrict__ cnt,
        int* __restrict__ lexcl, int* __restrict__ bsum) {
    __shared__ int wsum[16];
    int t = threadIdx.x, lane = t & 63, wid = t >> 6;
    int i = blockIdx.x * 1024 + t;
    int v = (i < N_NODES) ? cnt[i] : 0;
    int s = v;
#pragma unroll
    for (int off = 1; off < 64; off <<= 1) {
        int x = __shfl_up(s, off);
        if (lane >= off) s += x;
    }
    if (lane == 63) wsum[wid] = s;
    __syncthreads();
    if (t < 16) {
        int w = wsum[t];
#pragma unroll
        for (int off = 1; off < 16; off <<= 1) {
            int x = __shfl_up(w, off);
            if (t >= off) w += x;
        }
        wsum[t] = w;
    }
    __syncthreads();
    int waveoff = (wid == 0) ? 0 : wsum[wid - 1];
    int incl = s + waveoff;
    if (i < N_NODES) lexcl[i] = incl - v;
    if (t == 1023) bsum[blockIdx.x] = incl;
}

// fused top-scan + add: every block redundantly scans the 49 block sums (cheap)
__global__ __launch_bounds__(256) void k_scan_add(int* __restrict__ row_start,
        const int* __restrict__ bsum, int* __restrict__ cursor) {
    __shared__ int sb[64];
    __shared__ int stot;
    int t = threadIdx.x;
    if (t < 64) {
        int v = (t < NT) ? bsum[t] : 0;
        int s = v;
#pragma unroll
        for (int off = 1; off < 64; off <<= 1) {
            int x = __shfl_up(s, off);
            if (t >= off) s += x;
        }
        sb[t] = s - v;
        if (t == 63) stot = s;
    }
    __syncthreads();
    int i = blockIdx.x * 256 + t;
    if (i < N_NODES) {
        int v = row_start[i] + sb[i >> 10];
        row_start[i] = v;
        cursor[i] = v;
    }
    if (i == 0) row_start[N_NODES] = stot;
}

__global__ void k_scatter(const int* __restrict__ ei, int* __restrict__ cursor,
                          int* __restrict__ esrc) {
    int e = blockIdx.x * blockDim.x + threadIdx.x;
    if (e >= EP) return;
    int s, d; edge_sd(e, ei, s, d);
    int p = atomicAdd(&cursor[d], 1);
    esrc[p] = s;
}

// ------- layer 1 GEMM via MFMA bf16 (16x16x32) + fused edge histogram -------
__global__ __launch_bounds__(256) void k_gemm1(
        const float* __restrict__ x, const float* __restrict__ W1,
        const float* __restrict__ att_s, const float* __restrict__ att_d,
        unsigned short* __restrict__ xh1b, float* __restrict__ a_src, float* __restrict__ a_dst,
        const int* __restrict__ ei, int* __restrict__ cnt) {
    __shared__ float xs[16][68];          // padded x-tile (4.4 KB)
    int t = threadIdx.x;
    for (int e = blockIdx.x * 256 + t; e < EP; e += 256 * GMB) {
        int s, d; edge_sd(e, ei, s, d);
        atomicAdd(&cnt[d], 1);
    }
    int w = t >> 6, l = t & 63;
    int lo16 = l & 15, kg = l >> 4;       // B col / A row ; k-group
    short8 bfrag[4][2];
#pragma unroll
    for (int ct = 0; ct < 4; ++ct)
#pragma unroll
        for (int kh = 0; kh < 2; ++kh) {
            const float* wp = W1 + (size_t)(kh * 32 + kg * 8) * F1 + (w * 64 + ct * 16 + lo16);
            short8 f;
#pragma unroll
            for (int i = 0; i < 8; ++i) f[i] = (short)bf16rn(wp[(size_t)i * F1]);
            bfrag[ct][kh] = f;
        }
    float asv[4], adv[4];
#pragma unroll
    for (int ct = 0; ct < 4; ++ct) {
        asv[ct] = att_s[w * 64 + ct * 16 + lo16];
        adv[ct] = att_d[w * 64 + ct * 16 + lo16];
    }
    int sr = t >> 4, sc = (t & 15) * 4;   // staging coords
    for (int rt = blockIdx.x; rt < NRT; rt += GMB) {
        __syncthreads();                  // WAR on xs
        *(float4*)&xs[sr][sc] = *(const float4*)(x + (size_t)(rt * 16 + sr) * HID + sc);
        __syncthreads();
        short8 af[2];
#pragma unroll
        for (int kh = 0; kh < 2; ++kh) {
            const float* xp = &xs[lo16][kh * 32 + kg * 8];
            float4 u0 = *(const float4*)xp;
            float4 u1 = *(const float4*)(xp + 4);
            short8 f;
            f[0] = (short)bf16rn(u0.x); f[1] = (short)bf16rn(u0.y);
            f[2] = (short)bf16rn(u0.z); f[3] = (short)bf16rn(u0.w);
            f[4] = (short)bf16rn(u1.x); f[5] = (short)bf16rn(u1.y);
            f[6] = (short)bf16rn(u1.z); f[7] = (short)bf16rn(u1.w);
            af[kh] = f;
        }
        f32x4 acc[4];
#pragma unroll
        for (int ct = 0; ct < 4; ++ct) {
            acc[ct] = (f32x4){0.f, 0.f, 0.f, 0.f};
            acc[ct] = __builtin_amdgcn_mfma_f32_16x16x32_bf16(af[0], bfrag[ct][0], acc[ct], 0, 0, 0);
            acc[ct] = __builtin_amdgcn_mfma_f32_16x16x32_bf16(af[1], bfrag[ct][1], acc[ct], 0, 0, 0);
        }
#pragma unroll
        for (int reg = 0; reg < 4; ++reg) {
            int gr = rt * 16 + kg * 4 + reg;
#pragma unroll
            for (int ct = 0; ct < 4; ++ct)
                xh1b[(size_t)gr * F1 + w * 64 + ct * 16 + lo16] = bf16rn(acc[ct][reg]);
            float ps = acc[0][reg] * asv[0] + acc[1][reg] * asv[1]
                     + acc[2][reg] * asv[2] + acc[3][reg] * asv[3];
            float pd = acc[0][reg] * adv[0] + acc[1][reg] * adv[1]
                     + acc[2][reg] * adv[2] + acc[3][reg] * adv[3];
#pragma unroll
            for (int o = 1; o <= 8; o <<= 1) {
                ps += __shfl_xor(ps, o);
                pd += __shfl_xor(pd, o);
            }
            if (lo16 == 0) {
                a_src[gr * HEADS + w] = ps;
                a_dst[gr * HEADS + w] = pd;
            }
        }
    }
}

// ------- layer 1, wave-per-node: no-max softmax + wide gather + ELU + (h @ W2) -------
// lal padded [4][4][68]: hf slices on distinct banks -> conflict-free alpha reads.
__global__ __launch_bounds__(256) void k_csr1(
        const int* __restrict__ row_start, const int* __restrict__ esrc,
        const float* __restrict__ a_src, const float* __restrict__ a_dst,
        const unsigned short* __restrict__ xh1b, const float* __restrict__ b1,
        const float* __restrict__ W2, const float* __restrict__ att_s2,
        const float* __restrict__ att_d2,
        unsigned short* __restrict__ xh2b, float* __restrict__ a_src2,
        float* __restrict__ a_dst2) {
    int w = threadIdx.x >> 6, l = threadIdx.x & 63;
    int d = blockIdx.x * 4 + w;
    if (d >= N_NODES) return;
    int base = row_start[d], deg = row_start[d + 1] - base;
    __shared__ int   ls[4][64];
    __shared__ float lal[4][4][68];      // [wave][head][edge(+pad)]
    int h = l >> 4, e16 = l & 15;        // softmax mapping
    int eoff = l >> 5, fl = l & 31, hf = fl >> 3;   // gather mapping
    int* lsw = ls[w];
    float adh = a_dst[d * HEADS + h];
    float denl = 0.0f;
    float a0=0.f,a1=0.f,a2=0.f,a3=0.f,a4=0.f,a5=0.f,a6=0.f,a7=0.f;
    for (int c0 = 0; c0 < deg; c0 += 64) {
        int cn = min(64, deg - c0);
        if (l < cn) lsw[l] = esrc[base + c0 + l];
        // ---- single-pass softmax weights (no max subtraction; logits small) ----
        for (int j = e16; j < cn; j += 16) {
            float ev = a_src[lsw[j] * HEADS + h] + adh;
            ev = ev > 0.0f ? ev : SLOPE * ev;
            float wj = __expf(ev);
            lal[w][h][j] = wj;           // same-wave RAW below
            denl += wj;
        }
        // ---- wide gather: 2 edges per uint4 instr, 4 edges in flight ----
        const float* lalh = lal[w][hf];
        int j = 0;
        for (; j + 3 < cn; j += 4) {
            float wa = lalh[j + eoff], wb = lalh[j + 2 + eoff];
            uint4 pa = *(const uint4*)(xh1b + (size_t)lsw[j + eoff]     * F1 + 8 * fl);
            uint4 pb = *(const uint4*)(xh1b + (size_t)lsw[j + 2 + eoff] * F1 + 8 * fl);
            a0 += wa * bf_lo(pa.x); a1 += wa * bf_hi(pa.x);
            a2 += wa * bf_lo(pa.y); a3 += wa * bf_hi(pa.y);
            a4 += wa * bf_lo(pa.z); a5 += wa * bf_hi(pa.z);
            a6 += wa * bf_lo(pa.w); a7 += wa * bf_hi(pa.w);
            a0 += wb * bf_lo(pb.x); a1 += wb * bf_hi(pb.x);
            a2 += wb * bf_lo(pb.y); a3 += wb * bf_hi(pb.y);
            a4 += wb * bf_lo(pb.z); a5 += wb * bf_hi(pb.z);
            a6 += wb * bf_lo(pb.w); a7 += wb * bf_hi(pb.w);
        }
        for (; j + 1 < cn; j += 2) {
            float wa = lalh[j + eoff];
            uint4 pa = *(const uint4*)(xh1b + (size_t)lsw[j + eoff] * F1 + 8 * fl);
            a0 += wa * bf_lo(pa.x); a1 += wa * bf_hi(pa.x);
            a2 += wa * bf_lo(pa.y); a3 += wa * bf_hi(pa.y);
            a4 += wa * bf_lo(pa.z); a5 += wa * bf_hi(pa.z);
            a6 += wa * bf_lo(pa.w); a7 += wa * bf_hi(pa.w);
        }
        if (j < cn && eoff == 0) {       // odd tail: low half only
            float wa = lalh[j];
            uint4 pa = *(const uint4*)(xh1b + (size_t)lsw[j] * F1 + 8 * fl);
            a0 += wa * bf_lo(pa.x); a1 += wa * bf_hi(pa.x);
            a2 += wa * bf_lo(pa.y); a3 += wa * bf_hi(pa.y);
            a4 += wa * bf_lo(pa.z); a5 += wa * bf_hi(pa.z);
            a6 += wa * bf_lo(pa.w); a7 += wa * bf_hi(pa.w);
        }
    }
    // den: reduce within 16-lane head group, then fetch my gather-head's den
#pragma unroll
    for (int o = 8; o >= 1; o >>= 1) denl += __shfl_xor(denl, o);
    float dd = __shfl(denl, hf * 16);
    float inv = 1.0f / (dd + 1e-16f);
    // merge edge halves
    a0 += __shfl_xor(a0, 32); a1 += __shfl_xor(a1, 32);
    a2 += __shfl_xor(a2, 32); a3 += __shfl_xor(a3, 32);
    a4 += __shfl_xor(a4, 32); a5 += __shfl_xor(a5, 32);
    a6 += __shfl_xor(a6, 32); a7 += __shfl_xor(a7, 32);
    // bias + ELU for features 8*fl..8*fl+7
    float4 bb0 = *(const float4*)(b1 + 8 * fl);
    float4 bb1 = *(const float4*)(b1 + 8 * fl + 4);
    float v0 = a0 * inv + bb0.x, v1 = a1 * inv + bb0.y;
    float v2 = a2 * inv + bb0.z, v3 = a3 * inv + bb0.w;
    float v4 = a4 * inv + bb1.x, v5 = a5 * inv + bb1.y;
    float v6 = a6 * inv + bb1.z, v7 = a7 * inv + bb1.w;
    v0 = v0 > 0.0f ? v0 : (__expf(v0) - 1.0f);
    v1 = v1 > 0.0f ? v1 : (__expf(v1) - 1.0f);
    v2 = v2 > 0.0f ? v2 : (__expf(v2) - 1.0f);
    v3 = v3 > 0.0f ? v3 : (__expf(v3) - 1.0f);
    v4 = v4 > 0.0f ? v4 : (__expf(v4) - 1.0f);
    v5 = v5 > 0.0f ? v5 : (__expf(v5) - 1.0f);
    v6 = v6 > 0.0f ? v6 : (__expf(v6) - 1.0f);
    v7 = v7 > 0.0f ? v7 : (__expf(v7) - 1.0f);
    // ---- stage h row (same wave; lanes<32 hold the merged sums) ----
    float* hrow = &lal[w][0][0];          // flat reuse (>=256 floats)
    if (l < 32) {
        *(float4*)(hrow + 8 * fl)     = make_float4(v0, v1, v2, v3);
        *(float4*)(hrow + 8 * fl + 4) = make_float4(v4, v5, v6, v7);
    }
    // ---- projection: flat coalesced W2 (16KB; L1-resident after first wave) ----
    int k0 = l >> 2;                      // h index base (stride 16)
    int cg = (l & 3) * 4;                 // class-group base
    const float4* w4 = (const float4*)W2;
    float q0 = 0.0f, q1 = 0.0f, q2 = 0.0f, q3 = 0.0f;
#pragma unroll
    for (int j = 0; j < 16; ++j) {
        float hk = hrow[k0 + 16 * j];     // 16-addr broadcast, conflict-free
        float4 wv = w4[l + 64 * j];       // coalesced: bytes 16l + 1024j
        q0 += hk * wv.x; q1 += hk * wv.y; q2 += hk * wv.z; q3 += hk * wv.w;
    }
#pragma unroll
    for (int o = 4; o <= 32; o <<= 1) {   // reduce lanes sharing (l&3)
        q0 += __shfl_xor(q0, o); q1 += __shfl_xor(q1, o);
        q2 += __shfl_xor(q2, o); q3 += __shfl_xor(q3, o);
    }
    if (l < 4) {                          // lane l owns classes 4l..4l+3
        unsigned u0 = (unsigned)bf16rn(q0) | ((unsigned)bf16rn(q1) << 16);
        unsigned u1 = (unsigned)bf16rn(q2) | ((unsigned)bf16rn(q3) << 16);
        *(uint2*)(xh2b + (size_t)d * NC + 4 * l) = make_uint2(u0, u1);
        float ps = q0 * att_s2[cg] + q1 * att_s2[cg + 1]
                 + q2 * att_s2[cg + 2] + q3 * att_s2[cg + 3];
        float pd = q0 * att_d2[cg] + q1 * att_d2[cg + 1]
                 + q2 * att_d2[cg + 2] + q3 * att_d2[cg + 3];
        ps += __shfl_xor(ps, 1); ps += __shfl_xor(ps, 2);
        pd += __shfl_xor(pd, 1); pd += __shfl_xor(pd, 2);
        if (l == 0) { a_src2[d] = ps; a_dst2[d] = pd; }
    }
}

// ------- layer 2 fused: no-max softmax + wide gather + bias + log_softmax -------
// 4 waves/block, 1 node/wave; lane l -> edge slot l>>1, classes 8*(l&1)..+7
// (uint4 = half-row per lane, 32 edge slots in flight)
__global__ __launch_bounds__(256) void k_csr2(
        const int* __restrict__ row_start, const int* __restrict__ esrc,
        const float* __restrict__ a_src2, const float* __restrict__ a_dst2,
        const unsigned short* __restrict__ xh2b, const float* __restrict__ b2,
        float* __restrict__ out) {
    int w = threadIdx.x >> 6, l = threadIdx.x & 63;
    int d = blockIdx.x * 4 + w;
    if (d >= N_NODES) return;
    int base = row_start[d], deg = row_start[d + 1] - base;
    __shared__ int   ls[4][64];
    __shared__ float lal[4][64];
    float adh = a_dst2[d];
    int cp2 = l & 1, je = l >> 1;
    float denl = 0.0f;
    float a0=0.f,a1=0.f,a2=0.f,a3=0.f,a4=0.f,a5=0.f,a6=0.f,a7=0.f;
    for (int c0 = 0; c0 < deg; c0 += 64) {
        int cn = min(64, deg - c0);
        if (l < cn) {
            int s = esrc[base + c0 + l];
            ls[w][l] = s;
            float ev = a_src2[s] + adh;
            ev = ev > 0.0f ? ev : SLOPE * ev;
            float wj = __expf(ev);
            lal[w][l] = wj;          // same-wave RAW below
            denl += wj;
        }
        for (int j = je; j < cn; j += 32) {
            float wj = lal[w][j];
            uint4 pv = *(const uint4*)(xh2b + (size_t)ls[w][j] * NC + 8 * cp2);
            a0 += wj * bf_lo(pv.x); a1 += wj * bf_hi(pv.x);
            a2 += wj * bf_lo(pv.y); a3 += wj * bf_hi(pv.y);
            a4 += wj * bf_lo(pv.z); a5 += wj * bf_hi(pv.z);
            a6 += wj * bf_lo(pv.w); a7 += wj * bf_hi(pv.w);
        }
    }
#pragma unroll
    for (int o = 32; o >= 1; o >>= 1) denl += __shfl_xor(denl, o);
#pragma unroll
    for (int o = 2; o <= 32; o <<= 1) {           // reduce over the 32 je slots
        a0 += __shfl_xor(a0, o); a1 += __shfl_xor(a1, o);
        a2 += __shfl_xor(a2, o); a3 += __shfl_xor(a3, o);
        a4 += __shfl_xor(a4, o); a5 += __shfl_xor(a5, o);
        a6 += __shfl_xor(a6, o); a7 += __shfl_xor(a7, o);
    }
    float inv = 1.0f / (denl + 1e-16f);
    float v0 = a0 * inv + b2[8 * cp2 + 0];
    float v1 = a1 * inv + b2[8 * cp2 + 1];
    float v2 = a2 * inv + b2[8 * cp2 + 2];
    float v3 = a3 * inv + b2[8 * cp2 + 3];
    float v4 = a4 * inv + b2[8 * cp2 + 4];
    float v5 = a5 * inv + b2[8 * cp2 + 5];
    float v6 = a6 * inv + b2[8 * cp2 + 6];
    float v7 = a7 * inv + b2[8 * cp2 + 7];
    float mm = fmaxf(fmaxf(fmaxf(v0, v1), fmaxf(v2, v3)),
                     fmaxf(fmaxf(v4, v5), fmaxf(v6, v7)));
    mm = fmaxf(mm, __shfl_xor(mm, 1));
    float se = __expf(v0 - mm) + __expf(v1 - mm) + __expf(v2 - mm) + __expf(v3 - mm)
             + __expf(v4 - mm) + __expf(v5 - mm) + __expf(v6 - mm) + __expf(v7 - mm);
    se += __shfl_xor(se, 1);
    float lse = mm + logf(se);
    if (l < 2) {
        float* op = out + (size_t)d * NC + 8 * l;
        *(float4*)op       = make_float4(v0 - lse, v1 - lse, v2 - lse, v3 - lse);
        *(float4*)(op + 4) = make_float4(v4 - lse, v5 - lse, v6 - lse, v7 - lse);
    }
}

extern "C" void kernel_launch(void* const* d_in, const int* in_sizes, int n_in,
                              void* d_out, int out_size, void* d_ws, size_t ws_size,
                              hipStream_t stream) {
    const float* x        = (const float*)d_in[0];
    const int*   ei       = (const int*)d_in[1];
    const float* W1       = (const float*)d_in[2];
    const float* att_src1 = (const float*)d_in[3];
    const float* att_dst1 = (const float*)d_in[4];
    const float* b1       = (const float*)d_in[5];
    const float* W2       = (const float*)d_in[6];
    const float* att_src2 = (const float*)d_in[7];
    const float* att_dst2 = (const float*)d_in[8];
    const float* b2       = (const float*)d_in[9];
    float* out = (float*)d_out;

    // ---- workspace layout ----
    char* p = (char*)d_ws;
    unsigned short* xh1b  = (unsigned short*)p; p += (size_t)N_NODES * F1 * 2;   // 25.6MB
    unsigned short* xh2b  = (unsigned short*)p; p += (size_t)N_NODES * NC * 2;   // 1.6MB
    float* a_src1 = (float*)p; p += (size_t)N_NODES * HEADS * 4;
    float* a_dst1 = (float*)p; p += (size_t)N_NODES * HEADS * 4;
    float* a_src2 = (float*)p; p += (size_t)N_NODES * 4;
    float* a_dst2 = (float*)p; p += (size_t)N_NODES * 4;
    int* cnt       = (int*)p;  p += (size_t)N_NODES * 4;
    int* cursor    = (int*)p;  p += (size_t)N_NODES * 4;
    int* row_start = (int*)p;  p += (size_t)(N_NODES + 1) * 4;
    int* bsum      = (int*)p;  p += 64 * 4;
    int* esrc      = (int*)p;  p += (size_t)EP * 4;

    // ---- CSR build (hist fused into gemm1) ----
    hipMemsetAsync(cnt, 0, (size_t)N_NODES * 4, stream);
    k_gemm1<<<GMB, 256, 0, stream>>>(x, W1, att_src1, att_dst1, xh1b, a_src1, a_dst1,
                                     ei, cnt);
    k_scan_local<<<NT, 1024, 0, stream>>>(cnt, row_start, bsum);
    k_scan_add<<<(N_NODES + 255) / 256, 256, 0, stream>>>(row_start, bsum, cursor);
    k_scatter<<<(EP + 255) / 256, 256, 0, stream>>>(ei, cursor, esrc);

    // ---- layer 1 (+ fused layer-2 projection), wave-per-node ----
    k_csr1<<<(N_NODES + 3) / 4, 256, 0, stream>>>(row_start, esrc, a_src1, a_dst1, xh1b, b1,
                                                  W2, att_src2, att_dst2, xh2b, a_src2, a_dst2);

    // ---- layer 2 ----
    k_csr2<<<(N_NODES + 3) / 4, 256, 0, stream>>>(row_start, esrc, a_src2, a_dst2, xh2b, b2, out);
}

// Round 19
// 201.977 us; speedup vs baseline: 1.2052x; 1.0366x over previous
//
#include <hip/hip_runtime.h>
#include <hip/hip_bf16.h>
#include <math.h>

#define N_NODES 50000
#define N_EDGES 800000
#define EP (N_EDGES + N_NODES)   /* 850000 edges incl. self-loops */
#define HID 64
#define HEADS 4
#define F1 (HEADS * HID)         /* 256 */
#define NC 16
#define SLOPE 0.2f
#define NRT 3125                 /* row tiles: 50000 = 16*3125 exactly */
#define GMB 2048                 /* gemm grid blocks */
#define NT 49                    /* scan tiles = ceil(N/1024) */

typedef __attribute__((ext_vector_type(8))) short short8;
typedef __attribute__((ext_vector_type(4))) float f32x4;

// ---- bf16 helpers (round-to-nearest-even pack, exact unpack) ----
__device__ __forceinline__ unsigned short bf16rn(float f) {
    unsigned u = __float_as_uint(f);
    return (unsigned short)((u + 0x7fffu + ((u >> 16) & 1u)) >> 16);
}
__device__ __forceinline__ float bf_lo(unsigned p) { return __uint_as_float(p << 16); }
__device__ __forceinline__ float bf_hi(unsigned p) { return __uint_as_float(p & 0xffff0000u); }

__device__ __forceinline__ void edge_sd(int e, const int* __restrict__ ei, int& s, int& d) {
    if (e < N_EDGES) { s = ei[e]; d = ei[N_EDGES + e]; }
    else             { s = e - N_EDGES; d = s; }
}

// tile-local exclusive scan: 49 blocks x 1024 threads, 1024 elems/block
__global__ __launch_bounds__(1024) void k_scan_local(const int* __restrict__ cnt,
        int* __restrict__ lexcl, int* __restrict__ bsum) {
    __shared__ int wsum[16];
    int t = threadIdx.x, lane = t & 63, wid = t >> 6;
    int i = blockIdx.x * 1024 + t;
    int v = (i < N_NODES) ? cnt[i] : 0;
    int s = v;
#pragma unroll
    for (int off = 1; off < 64; off <<= 1) {
        int x = __shfl_up(s, off);
        if (lane >= off) s += x;
    }
    if (lane == 63) wsum[wid] = s;
    __syncthreads();
    if (t < 16) {
        int w = wsum[t];
#pragma unroll
        for (int off = 1; off < 16; off <<= 1) {
            int x = __shfl_up(w, off);
            if (t >= off) w += x;
        }
        wsum[t] = w;
    }
    __syncthreads();
    int waveoff = (wid == 0) ? 0 : wsum[wid - 1];
    int incl = s + waveoff;
    if (i < N_NODES) lexcl[i] = incl - v;
    if (t == 1023) bsum[blockIdx.x] = incl;
}

// fused top-scan + add: every block redundantly scans the 49 block sums (cheap)
__global__ __launch_bounds__(256) void k_scan_add(int* __restrict__ row_start,
        const int* __restrict__ bsum, int* __restrict__ cursor) {
    __shared__ int sb[64];
    __shared__ int stot;
    int t = threadIdx.x;
    if (t < 64) {
        int v = (t < NT) ? bsum[t] : 0;
        int s = v;
#pragma unroll
        for (int off = 1; off < 64; off <<= 1) {
            int x = __shfl_up(s, off);
            if (t >= off) s += x;
        }
        sb[t] = s - v;
        if (t == 63) stot = s;
    }
    __syncthreads();
    int i = blockIdx.x * 256 + t;
    if (i < N_NODES) {
        int v = row_start[i] + sb[i >> 10];
        row_start[i] = v;
        cursor[i] = v;
    }
    if (i == 0) row_start[N_NODES] = stot;
}

__global__ void k_scatter(const int* __restrict__ ei, int* __restrict__ cursor,
                          int* __restrict__ esrc) {
    int e = blockIdx.x * blockDim.x + threadIdx.x;
    if (e >= EP) return;
    int s, d; edge_sd(e, ei, s, d);
    int p = atomicAdd(&cursor[d], 1);
    esrc[p] = s;
}

// ------- layer 1 GEMM via MFMA bf16 (16x16x32) + fused edge histogram -------
__global__ __launch_bounds__(256) void k_gemm1(
        const float* __restrict__ x, const float* __restrict__ W1,
        const float* __restrict__ att_s, const float* __restrict__ att_d,
        unsigned short* __restrict__ xh1b, float* __restrict__ a_src, float* __restrict__ a_dst,
        const int* __restrict__ ei, int* __restrict__ cnt) {
    __shared__ float xs[16][68];          // padded x-tile (4.4 KB)
    int t = threadIdx.x;
    for (int e = blockIdx.x * 256 + t; e < EP; e += 256 * GMB) {
        int s, d; edge_sd(e, ei, s, d);
        atomicAdd(&cnt[d], 1);
    }
    int w = t >> 6, l = t & 63;
    int lo16 = l & 15, kg = l >> 4;       // B col / A row ; k-group
    short8 bfrag[4][2];
#pragma unroll
    for (int ct = 0; ct < 4; ++ct)
#pragma unroll
        for (int kh = 0; kh < 2; ++kh) {
            const float* wp = W1 + (size_t)(kh * 32 + kg * 8) * F1 + (w * 64 + ct * 16 + lo16);
            short8 f;
#pragma unroll
            for (int i = 0; i < 8; ++i) f[i] = (short)bf16rn(wp[(size_t)i * F1]);
            bfrag[ct][kh] = f;
        }
    float asv[4], adv[4];
#pragma unroll
    for (int ct = 0; ct < 4; ++ct) {
        asv[ct] = att_s[w * 64 + ct * 16 + lo16];
        adv[ct] = att_d[w * 64 + ct * 16 + lo16];
    }
    int sr = t >> 4, sc = (t & 15) * 4;   // staging coords
    for (int rt = blockIdx.x; rt < NRT; rt += GMB) {
        __syncthreads();                  // WAR on xs
        *(float4*)&xs[sr][sc] = *(const float4*)(x + (size_t)(rt * 16 + sr) * HID + sc);
        __syncthreads();
        short8 af[2];
#pragma unroll
        for (int kh = 0; kh < 2; ++kh) {
            const float* xp = &xs[lo16][kh * 32 + kg * 8];
            float4 u0 = *(const float4*)xp;
            float4 u1 = *(const float4*)(xp + 4);
            short8 f;
            f[0] = (short)bf16rn(u0.x); f[1] = (short)bf16rn(u0.y);
            f[2] = (short)bf16rn(u0.z); f[3] = (short)bf16rn(u0.w);
            f[4] = (short)bf16rn(u1.x); f[5] = (short)bf16rn(u1.y);
            f[6] = (short)bf16rn(u1.z); f[7] = (short)bf16rn(u1.w);
            af[kh] = f;
        }
        f32x4 acc[4];
#pragma unroll
        for (int ct = 0; ct < 4; ++ct) {
            acc[ct] = (f32x4){0.f, 0.f, 0.f, 0.f};
            acc[ct] = __builtin_amdgcn_mfma_f32_16x16x32_bf16(af[0], bfrag[ct][0], acc[ct], 0, 0, 0);
            acc[ct] = __builtin_amdgcn_mfma_f32_16x16x32_bf16(af[1], bfrag[ct][1], acc[ct], 0, 0, 0);
        }
#pragma unroll
        for (int reg = 0; reg < 4; ++reg) {
            int gr = rt * 16 + kg * 4 + reg;
#pragma unroll
            for (int ct = 0; ct < 4; ++ct)
                xh1b[(size_t)gr * F1 + w * 64 + ct * 16 + lo16] = bf16rn(acc[ct][reg]);
            float ps = acc[0][reg] * asv[0] + acc[1][reg] * asv[1]
                     + acc[2][reg] * asv[2] + acc[3][reg] * asv[3];
            float pd = acc[0][reg] * adv[0] + acc[1][reg] * adv[1]
                     + acc[2][reg] * adv[2] + acc[3][reg] * adv[3];
#pragma unroll
            for (int o = 1; o <= 8; o <<= 1) {
                ps += __shfl_xor(ps, o);
                pd += __shfl_xor(pd, o);
            }
            if (lo16 == 0) {
                a_src[gr * HEADS + w] = ps;
                a_dst[gr * HEADS + w] = pd;
            }
        }
    }
}

// ------- layer 1, wave-per-node: no-max softmax + wide gather + ELU + (h @ W2) -------
// lal padded [4][4][68]: hf slices on distinct banks -> conflict-free alpha reads.
__global__ __launch_bounds__(256) void k_csr1(
        const int* __restrict__ row_start, const int* __restrict__ esrc,
        const float* __restrict__ a_src, const float* __restrict__ a_dst,
        const unsigned short* __restrict__ xh1b, const float* __restrict__ b1,
        const float* __restrict__ W2, const float* __restrict__ att_s2,
        const float* __restrict__ att_d2,
        unsigned short* __restrict__ xh2b, float* __restrict__ a_src2,
        float* __restrict__ a_dst2) {
    int w = threadIdx.x >> 6, l = threadIdx.x & 63;
    int d = blockIdx.x * 4 + w;
    if (d >= N_NODES) return;
    int base = row_start[d], deg = row_start[d + 1] - base;
    __shared__ int   ls[4][64];
    __shared__ float lal[4][4][68];      // [wave][head][edge(+pad)]
    int h = l >> 4, e16 = l & 15;        // softmax mapping
    int eoff = l >> 5, fl = l & 31, hf = fl >> 3;   // gather mapping
    int* lsw = ls[w];
    float adh = a_dst[d * HEADS + h];
    float denl = 0.0f;
    float a0=0.f,a1=0.f,a2=0.f,a3=0.f,a4=0.f,a5=0.f,a6=0.f,a7=0.f;
    for (int c0 = 0; c0 < deg; c0 += 64) {
        int cn = min(64, deg - c0);
        if (l < cn) lsw[l] = esrc[base + c0 + l];
        // ---- single-pass softmax weights (no max subtraction; logits small) ----
        for (int j = e16; j < cn; j += 16) {
            float ev = a_src[lsw[j] * HEADS + h] + adh;
            ev = ev > 0.0f ? ev : SLOPE * ev;
            float wj = __expf(ev);
            lal[w][h][j] = wj;           // same-wave RAW below
            denl += wj;
        }
        // ---- wide gather: 2 edges per uint4 instr, 4 edges in flight ----
        const float* lalh = lal[w][hf];
        int j = 0;
        for (; j + 3 < cn; j += 4) {
            float wa = lalh[j + eoff], wb = lalh[j + 2 + eoff];
            uint4 pa = *(const uint4*)(xh1b + (size_t)lsw[j + eoff]     * F1 + 8 * fl);
            uint4 pb = *(const uint4*)(xh1b + (size_t)lsw[j + 2 + eoff] * F1 + 8 * fl);
            a0 += wa * bf_lo(pa.x); a1 += wa * bf_hi(pa.x);
            a2 += wa * bf_lo(pa.y); a3 += wa * bf_hi(pa.y);
            a4 += wa * bf_lo(pa.z); a5 += wa * bf_hi(pa.z);
            a6 += wa * bf_lo(pa.w); a7 += wa * bf_hi(pa.w);
            a0 += wb * bf_lo(pb.x); a1 += wb * bf_hi(pb.x);
            a2 += wb * bf_lo(pb.y); a3 += wb * bf_hi(pb.y);
            a4 += wb * bf_lo(pb.z); a5 += wb * bf_hi(pb.z);
            a6 += wb * bf_lo(pb.w); a7 += wb * bf_hi(pb.w);
        }
        for (; j + 1 < cn; j += 2) {
            float wa = lalh[j + eoff];
            uint4 pa = *(const uint4*)(xh1b + (size_t)lsw[j + eoff] * F1 + 8 * fl);
            a0 += wa * bf_lo(pa.x); a1 += wa * bf_hi(pa.x);
            a2 += wa * bf_lo(pa.y); a3 += wa * bf_hi(pa.y);
            a4 += wa * bf_lo(pa.z); a5 += wa * bf_hi(pa.z);
            a6 += wa * bf_lo(pa.w); a7 += wa * bf_hi(pa.w);
        }
        if (j < cn && eoff == 0) {       // odd tail: low half only
            float wa = lalh[j];
            uint4 pa = *(const uint4*)(xh1b + (size_t)lsw[j] * F1 + 8 * fl);
            a0 += wa * bf_lo(pa.x); a1 += wa * bf_hi(pa.x);
            a2 += wa * bf_lo(pa.y); a3 += wa * bf_hi(pa.y);
            a4 += wa * bf_lo(pa.z); a5 += wa * bf_hi(pa.z);
            a6 += wa * bf_lo(pa.w); a7 += wa * bf_hi(pa.w);
        }
    }
    // den: reduce within 16-lane head group, then fetch my gather-head's den
#pragma unroll
    for (int o = 8; o >= 1; o >>= 1) denl += __shfl_xor(denl, o);
    float dd = __shfl(denl, hf * 16);
    float inv = 1.0f / (dd + 1e-16f);
    // merge edge halves
    a0 += __shfl_xor(a0, 32); a1 += __shfl_xor(a1, 32);
    a2 += __shfl_xor(a2, 32); a3 += __shfl_xor(a3, 32);
    a4 += __shfl_xor(a4, 32); a5 += __shfl_xor(a5, 32);
    a6 += __shfl_xor(a6, 32); a7 += __shfl_xor(a7, 32);
    // bias + ELU for features 8*fl..8*fl+7
    float4 bb0 = *(const float4*)(b1 + 8 * fl);
    float4 bb1 = *(const float4*)(b1 + 8 * fl + 4);
    float v0 = a0 * inv + bb0.x, v1 = a1 * inv + bb0.y;
    float v2 = a2 * inv + bb0.z, v3 = a3 * inv + bb0.w;
    float v4 = a4 * inv + bb1.x, v5 = a5 * inv + bb1.y;
    float v6 = a6 * inv + bb1.z, v7 = a7 * inv + bb1.w;
    v0 = v0 > 0.0f ? v0 : (__expf(v0) - 1.0f);
    v1 = v1 > 0.0f ? v1 : (__expf(v1) - 1.0f);
    v2 = v2 > 0.0f ? v2 : (__expf(v2) - 1.0f);
    v3 = v3 > 0.0f ? v3 : (__expf(v3) - 1.0f);
    v4 = v4 > 0.0f ? v4 : (__expf(v4) - 1.0f);
    v5 = v5 > 0.0f ? v5 : (__expf(v5) - 1.0f);
    v6 = v6 > 0.0f ? v6 : (__expf(v6) - 1.0f);
    v7 = v7 > 0.0f ? v7 : (__expf(v7) - 1.0f);
    // ---- stage h row (same wave; lanes<32 hold the merged sums) ----
    float* hrow = &lal[w][0][0];          // flat reuse (>=256 floats)
    if (l < 32) {
        *(float4*)(hrow + 8 * fl)     = make_float4(v0, v1, v2, v3);
        *(float4*)(hrow + 8 * fl + 4) = make_float4(v4, v5, v6, v7);
    }
    // ---- projection: flat coalesced W2 (16KB; L1-resident after first wave) ----
    int k0 = l >> 2;                      // h index base (stride 16)
    int cg = (l & 3) * 4;                 // class-group base
    const float4* w4 = (const float4*)W2;
    float q0 = 0.0f, q1 = 0.0f, q2 = 0.0f, q3 = 0.0f;
#pragma unroll
    for (int j = 0; j < 16; ++j) {
        float hk = hrow[k0 + 16 * j];     // 16-addr broadcast, conflict-free
        float4 wv = w4[l + 64 * j];       // coalesced: bytes 16l + 1024j
        q0 += hk * wv.x; q1 += hk * wv.y; q2 += hk * wv.z; q3 += hk * wv.w;
    }
#pragma unroll
    for (int o = 4; o <= 32; o <<= 1) {   // reduce lanes sharing (l&3)
        q0 += __shfl_xor(q0, o); q1 += __shfl_xor(q1, o);
        q2 += __shfl_xor(q2, o); q3 += __shfl_xor(q3, o);
    }
    if (l < 4) {                          // lane l owns classes 4l..4l+3
        unsigned u0 = (unsigned)bf16rn(q0) | ((unsigned)bf16rn(q1) << 16);
        unsigned u1 = (unsigned)bf16rn(q2) | ((unsigned)bf16rn(q3) << 16);
        *(uint2*)(xh2b + (size_t)d * NC + 4 * l) = make_uint2(u0, u1);
        float ps = q0 * att_s2[cg] + q1 * att_s2[cg + 1]
                 + q2 * att_s2[cg + 2] + q3 * att_s2[cg + 3];
        float pd = q0 * att_d2[cg] + q1 * att_d2[cg + 1]
                 + q2 * att_d2[cg + 2] + q3 * att_d2[cg + 3];
        ps += __shfl_xor(ps, 1); ps += __shfl_xor(ps, 2);
        pd += __shfl_xor(pd, 1); pd += __shfl_xor(pd, 2);
        if (l == 0) { a_src2[d] = ps; a_dst2[d] = pd; }
    }
}

// ------- layer 2 fused: no-max softmax + wide gather + bias + log_softmax -------
__global__ __launch_bounds__(256) void k_csr2(
        const int* __restrict__ row_start, const int* __restrict__ esrc,
        const float* __restrict__ a_src2, const float* __restrict__ a_dst2,
        const unsigned short* __restrict__ xh2b, const float* __restrict__ b2,
        float* __restrict__ out) {
    int w = threadIdx.x >> 6, l = threadIdx.x & 63;
    int d = blockIdx.x * 4 + w;
    if (d >= N_NODES) return;
    int base = row_start[d], deg = row_start[d + 1] - base;
    __shared__ int   ls[4][64];
    __shared__ float lal[4][64];
    float adh = a_dst2[d];
    int cp4 = l & 3, je = l >> 2;
    float denl = 0.0f, a0 = 0.0f, a1 = 0.0f, a2 = 0.0f, a3 = 0.0f;
    for (int c0 = 0; c0 < deg; c0 += 64) {
        int cn = min(64, deg - c0);
        if (l < cn) {
            int s = esrc[base + c0 + l];
            ls[w][l] = s;
            float ev = a_src2[s] + adh;
            ev = ev > 0.0f ? ev : SLOPE * ev;
            float wj = __expf(ev);
            lal[w][l] = wj;          // same-wave RAW below
            denl += wj;
        }
        for (int j = je; j < cn; j += 16) {
            float wj = lal[w][j];
            uint2 pv = *(const uint2*)(xh2b + (size_t)ls[w][j] * NC + 4 * cp4);
            a0 += wj * bf_lo(pv.x); a1 += wj * bf_hi(pv.x);
            a2 += wj * bf_lo(pv.y); a3 += wj * bf_hi(pv.y);
        }
    }
#pragma unroll
    for (int o = 32; o >= 1; o >>= 1) denl += __shfl_xor(denl, o);
#pragma unroll
    for (int o = 4; o <= 32; o <<= 1) {           // reduce over the 16 je slots
        a0 += __shfl_xor(a0, o); a1 += __shfl_xor(a1, o);
        a2 += __shfl_xor(a2, o); a3 += __shfl_xor(a3, o);
    }
    float inv = 1.0f / (denl + 1e-16f);
    float v0 = a0 * inv + b2[4 * cp4 + 0];
    float v1 = a1 * inv + b2[4 * cp4 + 1];
    float v2 = a2 * inv + b2[4 * cp4 + 2];
    float v3 = a3 * inv + b2[4 * cp4 + 3];
    float mm = fmaxf(fmaxf(v0, v1), fmaxf(v2, v3));
    mm = fmaxf(mm, __shfl_xor(mm, 1));
    mm = fmaxf(mm, __shfl_xor(mm, 2));
    float se = __expf(v0 - mm) + __expf(v1 - mm) + __expf(v2 - mm) + __expf(v3 - mm);
    se += __shfl_xor(se, 1);
    se += __shfl_xor(se, 2);
    float lse = mm + logf(se);
    if (l < 4) *(float4*)(out + (size_t)d * NC + 4 * l)
                   = make_float4(v0 - lse, v1 - lse, v2 - lse, v3 - lse);
}

extern "C" void kernel_launch(void* const* d_in, const int* in_sizes, int n_in,
                              void* d_out, int out_size, void* d_ws, size_t ws_size,
                              hipStream_t stream) {
    const float* x        = (const float*)d_in[0];
    const int*   ei       = (const int*)d_in[1];
    const float* W1       = (const float*)d_in[2];
    const float* att_src1 = (const float*)d_in[3];
    const float* att_dst1 = (const float*)d_in[4];
    const float* b1       = (const float*)d_in[5];
    const float* W2       = (const float*)d_in[6];
    const float* att_src2 = (const float*)d_in[7];
    const float* att_dst2 = (const float*)d_in[8];
    const float* b2       = (const float*)d_in[9];
    float* out = (float*)d_out;

    // ---- workspace layout ----
    char* p = (char*)d_ws;
    unsigned short* xh1b  = (unsigned short*)p; p += (size_t)N_NODES * F1 * 2;   // 25.6MB
    unsigned short* xh2b  = (unsigned short*)p; p += (size_t)N_NODES * NC * 2;   // 1.6MB
    float* a_src1 = (float*)p; p += (size_t)N_NODES * HEADS * 4;
    float* a_dst1 = (float*)p; p += (size_t)N_NODES * HEADS * 4;
    float* a_src2 = (float*)p; p += (size_t)N_NODES * 4;
    float* a_dst2 = (float*)p; p += (size_t)N_NODES * 4;
    int* cnt       = (int*)p;  p += (size_t)N_NODES * 4;
    int* cursor    = (int*)p;  p += (size_t)N_NODES * 4;
    int* row_start = (int*)p;  p += (size_t)(N_NODES + 1) * 4;
    int* bsum      = (int*)p;  p += 64 * 4;
    int* esrc      = (int*)p;  p += (size_t)EP * 4;

    // ---- CSR build (hist fused into gemm1) ----
    hipMemsetAsync(cnt, 0, (size_t)N_NODES * 4, stream);
    k_gemm1<<<GMB, 256, 0, stream>>>(x, W1, att_src1, att_dst1, xh1b, a_src1, a_dst1,
                                     ei, cnt);
    k_scan_local<<<NT, 1024, 0, stream>>>(cnt, row_start, bsum);
    k_scan_add<<<(N_NODES + 255) / 256, 256, 0, stream>>>(row_start, bsum, cursor);
    k_scatter<<<(EP + 255) / 256, 256, 0, stream>>>(ei, cursor, esrc);

    // ---- layer 1 (+ fused layer-2 projection), wave-per-node ----
    k_csr1<<<(N_NODES + 3) / 4, 256, 0, stream>>>(row_start, esrc, a_src1, a_dst1, xh1b, b1,
                                                  W2, att_src2, att_dst2, xh2b, a_src2, a_dst2);

    // ---- layer 2 ----
    k_csr2<<<(N_NODES + 3) / 4, 256, 0, stream>>>(row_start, esrc, a_src2, a_dst2, xh2b, b2, out);
}